// Round 10
// baseline (1520.082 us; speedup 1.0000x reference)
//
#include <hip/hip_runtime.h>
#include <math.h>

// ---------------------------------------------------------------------------
// SNN forward, Round-10: FULLY FUSED. One launch runs, concurrently:
//   - 256 conv WGs (8/batch): per-step conv1(x[t]) -> lif0 -> conv2 -> lif2,
//     exchanging lif0 spike bitmasks between the batch's 8 WGs and publishing
//     lif2 spikes z(t) as tagged u64 words (publish-early: z(t) depends only
//     on state t-1).
//   - 640 rec stripe WGs polling the tagged z words (trailing conv by ~1 step)
//   - 64 reader WGs (fc + LI + output) trailing the rec archive.
// This overlaps the two latency-bound sequential chains (rec 425us, conv
// ~300us) that were stream-serialized in round 9, and deletes conv1_pool,
// c1buf, zbuf, chunking and all per-chunk launches.
// All arithmetic orders copied verbatim from round-9 (bit-exact).
// ---------------------------------------------------------------------------

#define BATCH 32
#define TSTEPS 150
#define ZSEQN 70
#define HID1 512
#define HID2 1024
#define K1CAT 582           // rows: [rec(512) | conv(70)]
#define K2CAT 1094          // rows: [rec(1024) | conv(70)]

#define N_W1T  (K1CAT*HID1)           // 297,984
#define N_W2T  (K2CAT*HID2)           // 1,120,256

// archives (u64 counts)
#define A1_U64  (BATCH*TSTEPS*32)     // rec role-1 masks      153,600
#define A0_U64  (BATCH*TSTEPS*16)     // rec role-0 masks       76,800
#define AC_U64  (BATCH*TSTEPS*8)      // conv z2 masks          38,400
#define AZ0_U64 (BATCH*TSTEPS*52)     // lif0 spike exchange   249,600
#define N_ARCH_U64 (A1_U64+A0_U64+AC_U64+AZ0_U64)   // 518,400 (4.15 MB)

typedef unsigned long long u64;

// -------------------------------------------------------------------- K0 ---
__global__ void prep_weights(const float* __restrict__ l1_in_w,
                             const float* __restrict__ l1_rec_w,
                             const float* __restrict__ cl_in_w,
                             const float* __restrict__ cl_rec_w,
                             float* __restrict__ w1t,
                             float* __restrict__ w2t) {
    int idx = blockIdx.x * blockDim.x + threadIdx.x;
    int stride = gridDim.x * blockDim.x;
    for (int e = idx; e < N_W1T; e += stride) {
        int j = e / HID1, o = e - j * HID1;
        w1t[e] = (j < HID1) ? l1_rec_w[o * HID1 + j] : l1_in_w[o * 70 + (j - HID1)];
    }
    for (int e = idx; e < N_W2T; e += stride) {
        int j = e / HID2, o = e - j * HID2;
        w2t[e] = (j < HID2) ? cl_rec_w[o * HID2 + j] : cl_in_w[o * 70 + (j - HID2)];
    }
}

__global__ void init_arch(u64* __restrict__ arch) {
    size_t idx = (size_t)blockIdx.x * blockDim.x + threadIdx.x;
    size_t stride = (size_t)gridDim.x * blockDim.x;
    for (size_t e = idx; e < N_ARCH_U64; e += stride) arch[e] = 0ull;
}

// ------------------------------------------------------------- helpers ---
__device__ __forceinline__ float4 f4add(float4 a, const float4 b) {
    a.x += b.x; a.y += b.y; a.z += b.z; a.w += b.w; return a;
}
__device__ __forceinline__ void ast64(u64* p, u64 v) {
    __hip_atomic_store(p, v, __ATOMIC_RELAXED, __HIP_MEMORY_SCOPE_AGENT);
}
__device__ __forceinline__ u64 ald64(const u64* p) {
    return __hip_atomic_load((u64*)p, __ATOMIC_RELAXED, __HIP_MEMORY_SCOPE_AGENT);
}

// ----------------------------------------------------------- conv body ---
// WG (w,b): owns lif0 oc-slice (4 or 3 of 30) and lif2 oc-slice (9 or 7 of 70).
__device__ __forceinline__ void conv_body(int w, int b,
        const float* __restrict__ x,  const float* __restrict__ w1,
        const float* __restrict__ b1, const float* __restrict__ w2,
        const float* __restrict__ b2,
        u64* __restrict__ az0,        // archz0 + b*150*52
        u64* __restrict__ ac,         // archc  + b*150*8
        float* smem) {
    const int OC1_ST = (w < 6) ? 4 * w : ((w == 6) ? 24 : 27);
    const int nOc1   = (w < 6) ? 4 : 3;
    const int nc1    = 49 * nOc1;
    const int WOFF   = (w < 6) ? 7 * w : ((w == 6) ? 42 : 47);
    const int ocStart2 = w * 9;
    const int nOc2   = (w == 7) ? 7 : 9;
    const int nrow3  = nOc1 * 21 * 3;

    float* img  = smem;                       // 2312
    float* w1s  = smem + 2312;                // 392
    float* crow = smem + 2704;                // 1764
    float* z0f  = smem + 4468;                // 1470
    float* part = smem + 5938;                // 2430
    float* red  = smem + 8368;                // 81
    unsigned int* pz = (unsigned int*)(smem + 8452);   // 52

    const int t = threadIdx.x;
    const int lane = t & 63, wv = t >> 6;

    for (int e = t; e < nOc1 * 98; e += 256) w1s[e] = w1[OC1_ST * 98 + e];

    float v0r = 0.f, i0r = 0.f;
    float b1r = (t < nc1) ? b1[OC1_ST + t / 49] : 0.f;
    float v2 = 0.f, i2 = 0.f;
    float bias2 = (t < nOc2) ? b2[ocStart2 + t] : 0.f;

    // per-thread z0f expansion map (cell e -> exchange word/bit)
    int wIdx[6], bIdx[6];
    #pragma unroll
    for (int k = 0; k < 6; ++k) {
        int e = t + k * 256;
        if (e < 1470) {
            int oc = e / 49;
            int wp = (oc < 24) ? (oc >> 2) : ((oc < 27) ? 6 : 7);
            int st = (wp < 6) ? 4 * wp : ((wp == 6) ? 24 : 27);
            int c = e - 49 * st;
            wIdx[k] = ((wp < 6) ? 7 * wp : ((wp == 6) ? 42 : 47)) + (c >> 5);
            bIdx[k] = c & 31;
        } else { wIdx[k] = 0; bIdx[k] = 0; }
    }
    // publish z2(0) = 0 (tag 1)
    if (t == 0) ast64(ac + w, ((u64)1 << 32));
    // initial img
    const float* xb = x + (size_t)b * TSTEPS * 2312;
    for (int e = t; e < 2312; e += 256) img[e] = xb[e];
    __syncthreads();

    for (int tt = 0; tt < TSTEPS; ++tt) {
        // ---- P0: img(t+1) prefetch to regs; lif0 spike decision + publish ----
        float pf[10];
        bool hpf = (tt + 1 < TSTEPS);
        if (hpf) {
            const float* xn = xb + (size_t)(tt + 1) * 2312;
            #pragma unroll
            for (int k = 0; k < 10; ++k) {
                int e = t + k * 256;
                pf[k] = (e < 2312) ? xn[e] : 0.f;
            }
        }
        bool sp0 = false;
        if (t < nc1) {
            float vd = v0r + 0.1f * (i0r - v0r);
            sp0 = (vd > 1.0f);
            v0r = sp0 ? 0.f : vd;
        }
        u64 mz = __ballot(sp0);
        if (lane == 0) {
            u64 tag = ((u64)(tt + 1)) << 32;
            int cbase = wv * 64;
            u64* wslot = az0 + (size_t)tt * 52 + WOFF + wv * 2;
            if (cbase < nc1)      ast64(wslot,     tag | (unsigned)(mz & 0xffffffffull));
            if (cbase + 32 < nc1) ast64(wslot + 1, tag | (unsigned)(mz >> 32));
        }
        // ---- P1: conv1 rows (order ic,ky,kx per output col — round-9 exact) ----
        if (t < nrow3) {
            int r = t / 3, h = t - r * 3;
            int ocl = r / 21, cy = r - ocl * 21, cx0 = 7 * h;
            float acc[7];
            #pragma unroll
            for (int c2 = 0; c2 < 7; ++c2) acc[c2] = 0.f;
            for (int ic = 0; ic < 2; ++ic) {
                const float* wrow = &w1s[ocl * 98 + ic * 49];
                const float* ib = &img[ic * 1156];
                #pragma unroll
                for (int ky = 0; ky < 7; ++ky) {
                    const float* ir = &ib[(cy + ky) * 34 + cx0];
                    float rr[13];
                    #pragma unroll
                    for (int j = 0; j < 13; ++j) rr[j] = ir[j];
                    #pragma unroll
                    for (int kx = 0; kx < 7; ++kx) {
                        float wvv = wrow[ky * 7 + kx];
                        #pragma unroll
                        for (int c2 = 0; c2 < 7; ++c2)
                            acc[c2] = fmaf(rr[c2 + kx], wvv, acc[c2]);
                    }
                }
            }
            #pragma unroll
            for (int c2 = 0; c2 < 7; ++c2) crow[r * 21 + cx0 + c2] = acc[c2];
        }
        __syncthreads();                                   // B1
        // ---- P2: pool + i0 update; wave3 polls the batch's z0 words ----
        if (t < nc1) {
            int ocl = t / 49, rr2 = t - ocl * 49, py = rr2 / 7, px = rr2 - py * 7;
            float m = -1e30f;
            #pragma unroll
            for (int dy = 0; dy < 3; ++dy)
                #pragma unroll
                for (int dx = 0; dx < 3; ++dx)
                    m = fmaxf(m, crow[(ocl * 21 + 3 * py + dy) * 21 + 3 * px + dx]);
            float c1 = m + b1r;
            float id = i0r - 0.2f * i0r;
            i0r = id + c1;
        }
        if (wv == 3) {
            bool need = lane < 52;
            u64 wd = 0;
            for (;;) {
                if (need) wd = ald64(az0 + (size_t)tt * 52 + lane);
                bool ok = !need || (unsigned)(wd >> 32) == (unsigned)(tt + 1);
                if (__ballot(ok) == ~0ull) break;
                __builtin_amdgcn_s_sleep(1);
            }
            if (need) pz[lane] = (unsigned)wd;
        }
        __syncthreads();                                   // B2
        // ---- P3: expand z0 bits -> floats; img(t+1) regs -> LDS ----
        #pragma unroll
        for (int k = 0; k < 6; ++k) {
            int e = t + k * 256;
            if (e < 1470) z0f[e] = ((pz[wIdx[k]] >> bIdx[k]) & 1u) ? 1.f : 0.f;
        }
        if (hpf) {
            #pragma unroll
            for (int k = 0; k < 10; ++k) {
                int e = t + k * 256;
                if (e < 2312) img[e] = pf[k];
            }
        }
        __syncthreads();                                   // B3
        // ---- P4: conv2 partials (round-9 exact; w2 from L2) ----
        #pragma unroll
        for (int pass = 0; pass < 2; ++pass) {
            int u = t + pass * 256;
            if (u < nOc2 * 30) {
                int ol = u / 30, ic = u - ol * 30;
                float zw[49];
                #pragma unroll
                for (int j = 0; j < 49; ++j) zw[j] = z0f[ic * 49 + j];
                float a[9];
                #pragma unroll
                for (int p = 0; p < 9; ++p) a[p] = 0.f;
                const float* wb = w2 + (size_t)(ocStart2 + ol) * 750 + ic * 25;
                #pragma unroll
                for (int ky = 0; ky < 5; ++ky)
                    #pragma unroll
                    for (int kx = 0; kx < 5; ++kx) {
                        float wvv = wb[ky * 5 + kx];
                        #pragma unroll
                        for (int cy2 = 0; cy2 < 3; ++cy2)
                            #pragma unroll
                            for (int cx2 = 0; cx2 < 3; ++cx2)
                                a[cy2 * 3 + cx2] = fmaf(zw[(cy2 + ky) * 7 + cx2 + kx], wvv, a[cy2 * 3 + cx2]);
                    }
                #pragma unroll
                for (int p = 0; p < 9; ++p) part[u * 9 + p] = a[p];
            }
        }
        __syncthreads();                                   // B4
        // ---- P5: serial-ic reduction (round-9 exact order) ----
        if (t < nOc2 * 9) {
            int ol = t / 9, pos = t - ol * 9;
            float s2 = 0.f;
            for (int ic = 0; ic < 30; ++ic) s2 += part[(ol * 30 + ic) * 9 + pos];
            red[t] = s2;
        }
        __syncthreads();                                   // B5
        // ---- P6: maxpool + lif2 + publish z2(tt+1) ----
        bool sp2 = false;
        if (t < nOc2) {
            float m = -1e30f;
            #pragma unroll
            for (int p = 0; p < 9; ++p) m = fmaxf(m, red[t * 9 + p]);
            float inp = m + bias2;
            float id2 = i2 - 0.2f * i2;
            i2 = id2 + inp;
            float vd2 = v2 + 0.1f * (i2 - v2);
            sp2 = (vd2 > 1.0f);
            v2 = sp2 ? 0.f : vd2;
        }
        if (tt + 1 < TSTEPS) {
            u64 mz2 = __ballot(sp2);
            if (t == 0)
                ast64(ac + (size_t)(tt + 1) * 8 + w,
                      (((u64)(tt + 2)) << 32) | (mz2 & 0x1ffull));
        }
        // no end barrier: crow/z0f/part reuse separated by >=2 barriers.
    }
}

// --------------------------------------------------------- stripe body ---
// ROLE1: 16 stripes x 64 cols; ROLE0: 4 stripes x 128 cols.
template <int ROLE>
__device__ __forceinline__ void stripe_body(int b, int s,
        const float* __restrict__ catT,
        u64* __restrict__ arch,              // this chain's rec archive
        const u64* __restrict__ ac,          // archc + b*150*8
        float* smem) {
    constexpr int N    = ROLE ? HID2 : HID1;
    constexpr int K    = ROLE ? K2CAT : K1CAT;
    constexpr int SW   = N / 32;
    constexpr int NW   = N / 32;
    constexpr int NWT  = NW + 3;
    constexpr int N4   = N / 4;
    constexpr int COLS = ROLE ? 64 : 128;
    constexpr int QC   = COLS / 4;
    constexpr int S    = 256 / QC;
    constexpr int PSTR = COLS + 4;

    float* part = smem;                                    // <=1088
    unsigned short* list = (unsigned short*)(smem + 1088); // K2CAT u16
    unsigned int* maskw = (unsigned int*)(smem + 1088 + 547);
    unsigned int* wprefix = maskw + 40;

    const int t = threadIdx.x;
    const int lane = t & 63, wv = t >> 6;
    const int aid = t / QC, qid = t - (t / QC) * QC;
    const int q0 = s * QC;

    const float4* __restrict__ catT4 = (const float4*)catT;
    float v = 0.f, iacc = 0.f;

    // ---- initial list: rec bits 0; conv mask from z(0) (tag 1) ----
    if (wv == 0) {
        bool needc = (lane >= 40 && lane < 48);
        u64 cw = 0;
        for (;;) {
            if (needc) cw = ald64(ac + (lane - 40));
            bool ok = !needc || (unsigned)(cw >> 32) == 1u;
            if (__ballot(ok) == ~0ull) break;
            __builtin_amdgcn_s_sleep(1);
        }
        if (lane < NW) maskw[lane] = 0u;
        u64 lo = 0, hi = 0;
        #pragma unroll
        for (int w = 0; w < 8; ++w) {
            u64 p = (u64)(__shfl((unsigned)cw, 40 + w) & 0x1ffu);
            if (w < 7) lo |= p << (9 * w);
            else { lo |= (p & 1ull) << 63; hi = p >> 1; }
        }
        if (lane == 0) {
            maskw[NW] = (unsigned)lo; maskw[NW + 1] = (unsigned)(lo >> 32);
            maskw[NW + 2] = (unsigned)hi;
        }
        unsigned val = (lane < NWT) ? __popc(maskw[lane]) : 0u;
        #pragma unroll
        for (int d = 1; d < 64; d <<= 1) {
            unsigned u2 = __shfl_up(val, d);
            if (lane >= d) val += u2;
        }
        if (lane < NWT) wprefix[lane + 1] = val;
        if (lane == 0) wprefix[0] = 0u;
    }
    __syncthreads();
    int A = wprefix[NWT];
    for (int jj = t; jj < K; jj += 256) {
        unsigned m = maskw[jj >> 5];
        if ((m >> (jj & 31)) & 1u)
            list[wprefix[jj >> 5] + __popc(m & ((1u << (jj & 31)) - 1u))] = (unsigned short)jj;
    }
    __syncthreads();

    for (int tt = 0; tt < TSTEPS; ++tt) {
        // ---- TOP: spike decision + publish (state t-1 only) ----
        float vd = v + 0.1f * (iacc - v);
        bool sp = (t < COLS) && (vd > 0.4f);
        float znew = sp ? 1.f : 0.f;
        if (t < COLS) v = sp ? 0.f : vd;
        u64 mz = __ballot(znew != 0.f);
        if (lane == 0 && wv < COLS / 64) {
            u64 tag = ((u64)(tt + 1)) << 32;
            u64* wslot = arch + (size_t)tt * SW + s * (COLS / 32) + wv * 2;
            ast64(wslot,     tag | (unsigned)(mz & 0xffffffffull));
            ast64(wslot + 1, tag | (unsigned)(mz >> 32));
        }
        // ---- gather active rows ----
        float4 s0 = {0.f, 0.f, 0.f, 0.f}, s1 = s0, s2 = s0, s3 = s0;
        int idx = aid;
        for (; idx + 3 * S < A; idx += 4 * S) {
            s0 = f4add(s0, catT4[(size_t)list[idx]         * N4 + q0 + qid]);
            s1 = f4add(s1, catT4[(size_t)list[idx + S]     * N4 + q0 + qid]);
            s2 = f4add(s2, catT4[(size_t)list[idx + 2 * S] * N4 + q0 + qid]);
            s3 = f4add(s3, catT4[(size_t)list[idx + 3 * S] * N4 + q0 + qid]);
        }
        for (; idx < A; idx += S) s0 = f4add(s0, catT4[(size_t)list[idx] * N4 + q0 + qid]);
        s0 = f4add(f4add(s0, s1), f4add(s2, s3));
        *(float4*)(part + aid * PSTR + 4 * qid) = s0;
        __syncthreads();                                   // B1
        if (t < COLS) {
            float cur = 0.f;
            #pragma unroll
            for (int a = 0; a < S; ++a) cur += part[a * PSTR + t];
            iacc = iacc - 0.2f * iacc + cur;
        }
        if (tt + 1 >= TSTEPS) break;
        // ---- wave0: poll peers' z(tt) + conv z(tt+1); build masks+prefix ----
        if (wv == 0) {
            bool needr = lane < SW;
            bool needc = (lane >= 40 && lane < 48);
            u64 wr = 0, wc = 0;
            for (;;) {
                if (needr) wr = ald64(arch + (size_t)tt * SW + lane);
                if (needc) wc = ald64(ac + (size_t)(tt + 1) * 8 + (lane - 40));
                bool ok = (!needr || (unsigned)(wr >> 32) == (unsigned)(tt + 1))
                       && (!needc || (unsigned)(wc >> 32) == (unsigned)(tt + 2));
                if (__ballot(ok) == ~0ull) break;
                __builtin_amdgcn_s_sleep(1);
            }
            if (needr) maskw[lane] = (unsigned)wr;
            u64 lo = 0, hi = 0;
            #pragma unroll
            for (int w = 0; w < 8; ++w) {
                u64 p = (u64)(__shfl((unsigned)wc, 40 + w) & 0x1ffu);
                if (w < 7) lo |= p << (9 * w);
                else { lo |= (p & 1ull) << 63; hi = p >> 1; }
            }
            if (lane == 0) {
                maskw[NW] = (unsigned)lo; maskw[NW + 1] = (unsigned)(lo >> 32);
                maskw[NW + 2] = (unsigned)hi;
            }
            unsigned val = (lane < NWT) ? __popc(maskw[lane]) : 0u;
            #pragma unroll
            for (int d = 1; d < 64; d <<= 1) {
                unsigned u2 = __shfl_up(val, d);
                if (lane >= d) val += u2;
            }
            if (lane < NWT) wprefix[lane + 1] = val;
            if (lane == 0) wprefix[0] = 0u;
        }
        __syncthreads();                                   // B2
        A = wprefix[NWT];
        for (int jj = t; jj < K; jj += 256) {
            unsigned m = maskw[jj >> 5];
            if ((m >> (jj & 31)) & 1u)
                list[wprefix[jj >> 5] + __popc(m & ((1u << (jj & 31)) - 1u))] = (unsigned short)jj;
        }
        __syncthreads();                                   // B3
    }
}

// --------------------------------------------------------- reader body ---
template <int ROLE>
__device__ __forceinline__ void readout_body(int b,
        const float* __restrict__ fcw,
        const u64* __restrict__ arch,
        float* __restrict__ out, float* smem) {
    constexpr int N  = ROLE ? HID2 : HID1;
    constexpr int SW = N / 32;
    constexpr int R  = ROLE ? 10 : 4;

    unsigned int* zw = (unsigned int*)smem;   // 32
    float* wpart = smem + 32;                 // 40
    float* mvals = smem + 72;                 // 10

    const int t = threadIdx.x;
    const int lane = t & 63, wv = t >> 6;
    float vli = 0.f, ili = 0.f, rmax = -1e30f;

    for (int tt = 0; tt < TSTEPS; ++tt) {
        if (wv == 0) {
            bool need = lane < SW;
            u64 w = 0;
            for (;;) {
                if (need) w = ald64(arch + (size_t)tt * SW + lane);
                bool ok = !need || (unsigned)(w >> 32) == (unsigned)(tt + 1);
                if (__ballot(ok) == ~0ull) break;
                __builtin_amdgcn_s_sleep(1);
            }
            if (need) zw[lane] = (unsigned)w;
        }
        __syncthreads();
        #pragma unroll
        for (int k = 0; k < R; ++k) {
            float p;
            if (ROLE) {
                unsigned bits = (zw[(t * 4) >> 5] >> ((t * 4) & 31)) & 0xFu;
                float4 w4 = ((const float4*)fcw)[k * (N / 4) + t];
                p = (bits & 1u ? w4.x : 0.f) + (bits & 2u ? w4.y : 0.f)
                  + (bits & 4u ? w4.z : 0.f) + (bits & 8u ? w4.w : 0.f);
            } else {
                unsigned bits = (zw[(t * 2) >> 5] >> ((t * 2) & 31)) & 0x3u;
                float2 w2 = ((const float2*)fcw)[k * (N / 2) + t];
                p = (bits & 1u ? w2.x : 0.f) + (bits & 2u ? w2.y : 0.f);
            }
            #pragma unroll
            for (int off = 32; off; off >>= 1) p += __shfl_xor(p, off);
            if (lane == 0) wpart[k * 4 + wv] = p;
        }
        __syncthreads();
        if (t < R) {
            float inp = wpart[t * 4] + wpart[t * 4 + 1] + wpart[t * 4 + 2] + wpart[t * 4 + 3];
            float vn = vli + 0.1f * (ili - vli);
            ili = ili - 0.2f * ili + inp;
            vli = vn;
            rmax = fmaxf(rmax, vn);
        }
    }
    if (ROLE) {
        if (t < 10) mvals[t] = rmax;
        __syncthreads();
        if (t < 10) {
            float M = -1e30f;
            #pragma unroll
            for (int k = 0; k < 10; ++k) M = fmaxf(M, mvals[k]);
            float ssum = 0.f;
            #pragma unroll
            for (int k = 0; k < 10; ++k) ssum += expf(mvals[k] - M);
            out[BATCH * 4 + b * 10 + t] = mvals[t] - M - logf(ssum);
        }
    } else if (t < 4) {
        out[b * 4 + t] = rmax;
    }
}

// -------------------------------------------------------------- fused ---
__global__ __launch_bounds__(256, 4) void snn_fused(
        const float* __restrict__ x,
        const float* __restrict__ w1, const float* __restrict__ b1,
        const float* __restrict__ w2, const float* __restrict__ b2,
        const float* __restrict__ fc_out_w, const float* __restrict__ cl_fc_w,
        const float* __restrict__ w1t, const float* __restrict__ w2t,
        u64* __restrict__ arch1, u64* __restrict__ arch0,
        u64* __restrict__ archc, u64* __restrict__ archz0,
        float* __restrict__ out) {
    __shared__ float smem[8704];      // 34.8 KB, carved per role
    int bid = blockIdx.x;
    if (bid < 256) {                                   // conv: bid%8 == b%8
        int w = bid >> 5, b = bid & 31;
        conv_body(w, b, x, w1, b1, w2, b2,
                  archz0 + (size_t)b * TSTEPS * 52,
                  archc + (size_t)b * TSTEPS * 8, smem);
    } else if (bid < 768) {                            // role-1 stripes
        int idx = bid - 256;
        int s = idx >> 5, b = idx & 31;
        stripe_body<1>(b, s, w2t, arch1 + (size_t)b * TSTEPS * 32,
                       archc + (size_t)b * TSTEPS * 8, smem);
    } else if (bid < 896) {                            // role-0 stripes
        int idx = bid - 768;
        int s = idx >> 5, b = idx & 31;
        stripe_body<0>(b, s, w1t, arch0 + (size_t)b * TSTEPS * 16,
                       archc + (size_t)b * TSTEPS * 8, smem);
    } else if (bid < 928) {
        int b = bid - 896;
        readout_body<1>(b, cl_fc_w, arch1 + (size_t)b * TSTEPS * 32, out, smem);
    } else {
        int b = bid - 928;
        readout_body<0>(b, fc_out_w, arch0 + (size_t)b * TSTEPS * 16, out, smem);
    }
}

// ---------------------------------------------------------------------------
extern "C" void kernel_launch(void* const* d_in, const int* in_sizes, int n_in,
                              void* d_out, int out_size, void* d_ws, size_t ws_size,
                              hipStream_t stream) {
    const float* x        = (const float*)d_in[0];
    const float* w1       = (const float*)d_in[1];
    const float* b1       = (const float*)d_in[2];
    const float* w2       = (const float*)d_in[3];
    const float* b2       = (const float*)d_in[4];
    const float* l1_in_w  = (const float*)d_in[5];
    const float* l1_rec_w = (const float*)d_in[6];
    const float* fc_out_w = (const float*)d_in[7];
    const float* cl_in_w  = (const float*)d_in[8];
    const float* cl_rec_w = (const float*)d_in[9];
    const float* cl_fc_w  = (const float*)d_in[10];
    float* out = (float*)d_out;

    u64* arch1  = (u64*)d_ws;
    u64* arch0  = arch1 + A1_U64;
    u64* archc  = arch0 + A0_U64;
    u64* archz0 = archc + AC_U64;
    float* w1t  = (float*)(archz0 + AZ0_U64);
    float* w2t  = w1t + N_W1T;

    prep_weights<<<dim3(512), dim3(256), 0, stream>>>(l1_in_w, l1_rec_w,
                                                      cl_in_w, cl_rec_w, w1t, w2t);
    init_arch<<<dim3(512), dim3(256), 0, stream>>>(arch1);
    snn_fused<<<dim3(960), dim3(256), 0, stream>>>(x, w1, b1, w2, b2,
                                                   fc_out_w, cl_fc_w, w1t, w2t,
                                                   arch1, arch0, archc, archz0, out);
}

// Round 11
// 715.267 us; speedup vs baseline: 2.1252x; 2.1252x over previous
//
#include <hip/hip_runtime.h>
#include <math.h>

// ---------------------------------------------------------------------------
// SNN forward, Round-11: partial fusion done right.
//   kernel 1: prep_weights, init_arch (tiny)
//   kernel 2: conv1_pool (throughput-parallel, unchanged from round 9)
//   kernel 3: snn_fused — 960 WGs, all co-resident (16KB LDS, lb(256,4)):
//     256 conv WGs: round-9 conv2_chain semantics (PRIVATE full lif0 state,
//       c1 from c1buf, no conv-side cross-WG sync) publishing tagged z2 words
//     512 role-1 + 128 role-0 rec stripes polling z2 + peer masks (round 8)
//     64 reader WGs (fc + LI + output)
// Round-10 failed because splitting lif0 across WGs added a per-step LLC
// exchange (archz0; WRITE_SIZE 190MB, 7e7 bank conflicts from in-step conv1).
// Here conv WGs free-run ahead; rec's 2.8us/step is the only critical path.
// ---------------------------------------------------------------------------

#define BATCH 32
#define TSTEPS 150
#define C1N 1470
#define ZSEQN 70
#define HID1 512
#define HID2 1024
#define K1CAT 582           // rows: [rec(512) | conv(70)]
#define K2CAT 1094          // rows: [rec(1024) | conv(70)]

#define N_W1T  (K1CAT*HID1)           // 297,984
#define N_W2T  (K2CAT*HID2)           // 1,120,256

#define A1_U64  (BATCH*TSTEPS*32)     // 153,600
#define A0_U64  (BATCH*TSTEPS*16)     // 76,800
#define AC_U64  (BATCH*TSTEPS*8)      // 38,400
#define N_ARCH_U64 (A1_U64+A0_U64+AC_U64)   // 268,800 u64 = 2.15 MB

typedef unsigned long long u64;

// -------------------------------------------------------------------- K0 ---
__global__ void prep_weights(const float* __restrict__ l1_in_w,
                             const float* __restrict__ l1_rec_w,
                             const float* __restrict__ cl_in_w,
                             const float* __restrict__ cl_rec_w,
                             float* __restrict__ w1t,
                             float* __restrict__ w2t) {
    int idx = blockIdx.x * blockDim.x + threadIdx.x;
    int stride = gridDim.x * blockDim.x;
    for (int e = idx; e < N_W1T; e += stride) {
        int j = e / HID1, o = e - j * HID1;
        w1t[e] = (j < HID1) ? l1_rec_w[o * HID1 + j] : l1_in_w[o * 70 + (j - HID1)];
    }
    for (int e = idx; e < N_W2T; e += stride) {
        int j = e / HID2, o = e - j * HID2;
        w2t[e] = (j < HID2) ? cl_rec_w[o * HID2 + j] : cl_in_w[o * 70 + (j - HID2)];
    }
}

__global__ void init_arch(u64* __restrict__ arch) {
    size_t idx = (size_t)blockIdx.x * blockDim.x + threadIdx.x;
    size_t stride = (size_t)gridDim.x * blockDim.x;
    for (size_t e = idx; e < N_ARCH_U64; e += stride) arch[e] = 0ull;
}

// -------------------------------------------------------------------- K1 ---
__global__ __launch_bounds__(640) void conv1_pool(const float* __restrict__ x,
                                                  const float* __restrict__ w1,
                                                  const float* __restrict__ b1,
                                                  float* __restrict__ c1buf,
                                                  int b0) {
    __shared__ float img[2 * 34 * 34];
    __shared__ float w1s[30 * 2 * 49];
    __shared__ float crow[630 * 21];
    int bid = blockIdx.x;
    int bl = bid / TSTEPS, t = bid - bl * TSTEPS;
    int tid = threadIdx.x;
    const float* xin = x + ((size_t)(b0 + bl) * TSTEPS + t) * 2312;
    for (int e = tid; e < 2312; e += 640) img[e] = xin[e];
    for (int e = tid; e < 2940; e += 640) w1s[e] = w1[e];
    __syncthreads();
    if (tid < 630) {
        int oc = tid / 21, cy = tid - oc * 21;
        float acc[21];
        #pragma unroll
        for (int j = 0; j < 21; ++j) acc[j] = 0.f;
        #pragma unroll
        for (int ic = 0; ic < 2; ++ic) {
            const float* irow0 = &img[ic * 1156];
            const float* wrow = &w1s[(oc * 2 + ic) * 49];
            #pragma unroll
            for (int ky = 0; ky < 7; ++ky) {
                const float* ir = &irow0[(cy + ky) * 34];
                float r[27];
                #pragma unroll
                for (int j = 0; j < 27; ++j) r[j] = ir[j];
                #pragma unroll
                for (int kx = 0; kx < 7; ++kx) {
                    float w = wrow[ky * 7 + kx];
                    #pragma unroll
                    for (int cx = 0; cx < 21; ++cx)
                        acc[cx] = fmaf(r[cx + kx], w, acc[cx]);
                }
            }
        }
        #pragma unroll
        for (int cx = 0; cx < 21; ++cx) crow[tid * 21 + cx] = acc[cx];
    }
    __syncthreads();
    float* c1 = c1buf + (size_t)bid * C1N;
    for (int p = tid; p < C1N; p += 640) {
        int oc = p / 49; int r = p - oc * 49; int py = r / 7, px = r - py * 7;
        float m = -1e30f;
        #pragma unroll
        for (int dy = 0; dy < 3; ++dy) {
            int rowid = oc * 21 + 3 * py + dy;
            #pragma unroll
            for (int dx = 0; dx < 3; ++dx)
                m = fmaxf(m, crow[rowid * 21 + 3 * px + dx]);
        }
        c1[p] = m + b1[oc];
    }
}

// ------------------------------------------------------------- helpers ---
__device__ __forceinline__ float4 f4add(float4 a, const float4 b) {
    a.x += b.x; a.y += b.y; a.z += b.z; a.w += b.w; return a;
}
__device__ __forceinline__ void ast64(u64* p, u64 v) {
    __hip_atomic_store(p, v, __ATOMIC_RELAXED, __HIP_MEMORY_SCOPE_AGENT);
}
__device__ __forceinline__ u64 ald64(const u64* p) {
    return __hip_atomic_load((u64*)p, __ATOMIC_RELAXED, __HIP_MEMORY_SCOPE_AGENT);
}

// ----------------------------------------------------------- conv body ---
// Round-9 conv2_chain at 256 threads: private full lif0 state (regs),
// c1 register prefetch, conv2 partials in 2 passes (w2 from L2), publishes
// z2 as tagged u64 (publish-next-step trick, verified round 10).
__device__ __forceinline__ void conv_body(int w, int bl,
        const float* __restrict__ w2, const float* __restrict__ b2,
        const float* __restrict__ c1buf,
        u64* __restrict__ ac, float* smem) {
    const int ocStart2 = w * 9;
    const int nOc2 = (w == 7) ? 7 : 9;
    float* z0f  = smem;            // 1470
    float* part = smem + 1472;     // 2430
    float* red  = smem + 3904;     // 81

    const int t = threadIdx.x;
    float v0r[6], i0r[6], cf[6];
    #pragma unroll
    for (int k = 0; k < 6; ++k) { v0r[k] = 0.f; i0r[k] = 0.f; }
    float v2 = 0.f, i2 = 0.f;
    float bias2 = (t < nOc2) ? b2[ocStart2 + t] : 0.f;
    const float* c1 = c1buf + (size_t)bl * TSTEPS * C1N;
    #pragma unroll
    for (int k = 0; k < 6; ++k) {
        int e = t + k * 256;
        cf[k] = (e < C1N) ? c1[e] : 0.f;
    }
    if (t == 0) ast64(ac + w, ((u64)1 << 32));   // z2(0) = 0, tag 1
    __syncthreads();

    for (int tt = 0; tt < TSTEPS; ++tt) {
        // ---- A: prefetch c1(tt+1); lif0 update (round-9 order) -> z0f ----
        float nf[6];
        bool h = (tt + 1 < TSTEPS);
        if (h) {
            const float* c1n = c1 + (size_t)(tt + 1) * C1N;
            #pragma unroll
            for (int k = 0; k < 6; ++k) {
                int e = t + k * 256;
                nf[k] = (e < C1N) ? c1n[e] : 0.f;
            }
        }
        #pragma unroll
        for (int k = 0; k < 6; ++k) {
            int e = t + k * 256;
            if (e < C1N) {
                float vd = v0r[k] + 0.1f * (i0r[k] - v0r[k]);
                bool sp = (vd > 1.0f);
                v0r[k] = sp ? 0.f : vd;
                i0r[k] = i0r[k] - 0.2f * i0r[k] + cf[k];
                z0f[e] = sp ? 1.f : 0.f;
            }
        }
        __syncthreads();                                   // B1: z0f ready
        // ---- B: conv2 partials (2 passes; round-9 arithmetic) ----
        #pragma unroll
        for (int pass = 0; pass < 2; ++pass) {
            int u = t + pass * 256;
            if (u < nOc2 * 30) {
                int ol = u / 30, ic = u - ol * 30;
                float zw[49];
                #pragma unroll
                for (int j = 0; j < 49; ++j) zw[j] = z0f[ic * 49 + j];
                float a[9];
                #pragma unroll
                for (int p = 0; p < 9; ++p) a[p] = 0.f;
                const float* wb = w2 + (size_t)(ocStart2 + ol) * 750 + ic * 25;
                #pragma unroll
                for (int ky = 0; ky < 5; ++ky)
                    #pragma unroll
                    for (int kx = 0; kx < 5; ++kx) {
                        float wvv = wb[ky * 5 + kx];
                        #pragma unroll
                        for (int cy = 0; cy < 3; ++cy)
                            #pragma unroll
                            for (int cx = 0; cx < 3; ++cx)
                                a[cy * 3 + cx] = fmaf(zw[(cy + ky) * 7 + cx + kx], wvv, a[cy * 3 + cx]);
                    }
                #pragma unroll
                for (int p = 0; p < 9; ++p) part[u * 9 + p] = a[p];
            }
        }
        __syncthreads();                                   // B2: part ready
        // ---- C: serial-ic reduction ----
        if (t < nOc2 * 9) {
            int ol = t / 9, pos = t - ol * 9;
            float s2 = 0.f;
            for (int ic = 0; ic < 30; ++ic) s2 += part[(ol * 30 + ic) * 9 + pos];
            red[t] = s2;
        }
        __syncthreads();                                   // B3: red ready
        // ---- D: maxpool + lif2 + publish z2(tt+1) (round-10 verified) ----
        bool sp2 = false;
        if (t < nOc2) {
            float m = -1e30f;
            #pragma unroll
            for (int p = 0; p < 9; ++p) m = fmaxf(m, red[t * 9 + p]);
            float inp = m + bias2;
            float id2 = i2 - 0.2f * i2;
            i2 = id2 + inp;
            float vd2 = v2 + 0.1f * (i2 - v2);
            sp2 = (vd2 > 1.0f);
            v2 = sp2 ? 0.f : vd2;
        }
        if (tt + 1 < TSTEPS) {
            u64 mz2 = __ballot(sp2);
            if (t == 0)
                ast64(ac + (size_t)(tt + 1) * 8 + w,
                      (((u64)(tt + 2)) << 32) | (mz2 & 0x1ffull));
        }
        #pragma unroll
        for (int k = 0; k < 6; ++k) cf[k] = nf[k];
        // z0f rewrite next A is >=2 barriers after its readers (P4 of this
        // step); part/red likewise — 3 barriers/step is hazard-free.
    }
}

// --------------------------------------------------------- stripe body ---
// ROLE1: 16 stripes x 64 cols; ROLE0: 4 stripes x 128 cols. (round 10 code)
template <int ROLE>
__device__ __forceinline__ void stripe_body(int b, int s,
        const float* __restrict__ catT,
        u64* __restrict__ arch,
        const u64* __restrict__ ac,
        float* smem) {
    constexpr int N    = ROLE ? HID2 : HID1;
    constexpr int K    = ROLE ? K2CAT : K1CAT;
    constexpr int SW   = N / 32;
    constexpr int NW   = N / 32;
    constexpr int NWT  = NW + 3;
    constexpr int N4   = N / 4;
    constexpr int COLS = ROLE ? 64 : 128;
    constexpr int QC   = COLS / 4;
    constexpr int S    = 256 / QC;
    constexpr int PSTR = COLS + 4;

    float* part = smem;                                    // <=1088
    unsigned short* list = (unsigned short*)(smem + 1088); // K2CAT u16
    unsigned int* maskw = (unsigned int*)(smem + 1088 + 547);
    unsigned int* wprefix = maskw + 40;

    const int t = threadIdx.x;
    const int lane = t & 63, wv = t >> 6;
    const int aid = t / QC, qid = t - (t / QC) * QC;
    const int q0 = s * QC;

    const float4* __restrict__ catT4 = (const float4*)catT;
    float v = 0.f, iacc = 0.f;

    // ---- initial list: rec bits 0; conv mask from z(0) (tag 1) ----
    if (wv == 0) {
        bool needc = (lane >= 40 && lane < 48);
        u64 cw = 0;
        for (;;) {
            if (needc) cw = ald64(ac + (lane - 40));
            bool ok = !needc || (unsigned)(cw >> 32) == 1u;
            if (__ballot(ok) == ~0ull) break;
            __builtin_amdgcn_s_sleep(1);
        }
        if (lane < NW) maskw[lane] = 0u;
        u64 lo = 0, hi = 0;
        #pragma unroll
        for (int w = 0; w < 8; ++w) {
            u64 p = (u64)(__shfl((unsigned)cw, 40 + w) & 0x1ffu);
            if (w < 7) lo |= p << (9 * w);
            else { lo |= (p & 1ull) << 63; hi = p >> 1; }
        }
        if (lane == 0) {
            maskw[NW] = (unsigned)lo; maskw[NW + 1] = (unsigned)(lo >> 32);
            maskw[NW + 2] = (unsigned)hi;
        }
        unsigned val = (lane < NWT) ? __popc(maskw[lane]) : 0u;
        #pragma unroll
        for (int d = 1; d < 64; d <<= 1) {
            unsigned u2 = __shfl_up(val, d);
            if (lane >= d) val += u2;
        }
        if (lane < NWT) wprefix[lane + 1] = val;
        if (lane == 0) wprefix[0] = 0u;
    }
    __syncthreads();
    int A = wprefix[NWT];
    for (int jj = t; jj < K; jj += 256) {
        unsigned m = maskw[jj >> 5];
        if ((m >> (jj & 31)) & 1u)
            list[wprefix[jj >> 5] + __popc(m & ((1u << (jj & 31)) - 1u))] = (unsigned short)jj;
    }
    __syncthreads();

    for (int tt = 0; tt < TSTEPS; ++tt) {
        // ---- TOP: spike decision + publish (state t-1 only) ----
        float vd = v + 0.1f * (iacc - v);
        bool sp = (t < COLS) && (vd > 0.4f);
        float znew = sp ? 1.f : 0.f;
        if (t < COLS) v = sp ? 0.f : vd;
        u64 mz = __ballot(znew != 0.f);
        if (lane == 0 && wv < COLS / 64) {
            u64 tag = ((u64)(tt + 1)) << 32;
            u64* wslot = arch + (size_t)tt * SW + s * (COLS / 32) + wv * 2;
            ast64(wslot,     tag | (unsigned)(mz & 0xffffffffull));
            ast64(wslot + 1, tag | (unsigned)(mz >> 32));
        }
        // ---- gather active rows ----
        float4 s0 = {0.f, 0.f, 0.f, 0.f}, s1 = s0, s2 = s0, s3 = s0;
        int idx = aid;
        for (; idx + 3 * S < A; idx += 4 * S) {
            s0 = f4add(s0, catT4[(size_t)list[idx]         * N4 + q0 + qid]);
            s1 = f4add(s1, catT4[(size_t)list[idx + S]     * N4 + q0 + qid]);
            s2 = f4add(s2, catT4[(size_t)list[idx + 2 * S] * N4 + q0 + qid]);
            s3 = f4add(s3, catT4[(size_t)list[idx + 3 * S] * N4 + q0 + qid]);
        }
        for (; idx < A; idx += S) s0 = f4add(s0, catT4[(size_t)list[idx] * N4 + q0 + qid]);
        s0 = f4add(f4add(s0, s1), f4add(s2, s3));
        *(float4*)(part + aid * PSTR + 4 * qid) = s0;
        __syncthreads();                                   // B1
        if (t < COLS) {
            float cur = 0.f;
            #pragma unroll
            for (int a = 0; a < S; ++a) cur += part[a * PSTR + t];
            iacc = iacc - 0.2f * iacc + cur;
        }
        if (tt + 1 >= TSTEPS) break;
        // ---- wave0: poll peers' z(tt) + conv z(tt+1) ----
        if (wv == 0) {
            bool needr = lane < SW;
            bool needc = (lane >= 40 && lane < 48);
            u64 wr = 0, wc = 0;
            for (;;) {
                if (needr) wr = ald64(arch + (size_t)tt * SW + lane);
                if (needc) wc = ald64(ac + (size_t)(tt + 1) * 8 + (lane - 40));
                bool ok = (!needr || (unsigned)(wr >> 32) == (unsigned)(tt + 1))
                       && (!needc || (unsigned)(wc >> 32) == (unsigned)(tt + 2));
                if (__ballot(ok) == ~0ull) break;
                __builtin_amdgcn_s_sleep(1);
            }
            if (needr) maskw[lane] = (unsigned)wr;
            u64 lo = 0, hi = 0;
            #pragma unroll
            for (int w = 0; w < 8; ++w) {
                u64 p = (u64)(__shfl((unsigned)wc, 40 + w) & 0x1ffu);
                if (w < 7) lo |= p << (9 * w);
                else { lo |= (p & 1ull) << 63; hi = p >> 1; }
            }
            if (lane == 0) {
                maskw[NW] = (unsigned)lo; maskw[NW + 1] = (unsigned)(lo >> 32);
                maskw[NW + 2] = (unsigned)hi;
            }
            unsigned val = (lane < NWT) ? __popc(maskw[lane]) : 0u;
            #pragma unroll
            for (int d = 1; d < 64; d <<= 1) {
                unsigned u2 = __shfl_up(val, d);
                if (lane >= d) val += u2;
            }
            if (lane < NWT) wprefix[lane + 1] = val;
            if (lane == 0) wprefix[0] = 0u;
        }
        __syncthreads();                                   // B2
        A = wprefix[NWT];
        for (int jj = t; jj < K; jj += 256) {
            unsigned m = maskw[jj >> 5];
            if ((m >> (jj & 31)) & 1u)
                list[wprefix[jj >> 5] + __popc(m & ((1u << (jj & 31)) - 1u))] = (unsigned short)jj;
        }
        __syncthreads();                                   // B3
    }
}

// --------------------------------------------------------- reader body ---
template <int ROLE>
__device__ __forceinline__ void readout_body(int b,
        const float* __restrict__ fcw,
        const u64* __restrict__ arch,
        float* __restrict__ out, float* smem) {
    constexpr int N  = ROLE ? HID2 : HID1;
    constexpr int SW = N / 32;
    constexpr int R  = ROLE ? 10 : 4;

    unsigned int* zw = (unsigned int*)smem;   // 32
    float* wpart = smem + 32;                 // 40
    float* mvals = smem + 72;                 // 10

    const int t = threadIdx.x;
    const int lane = t & 63, wv = t >> 6;
    float vli = 0.f, ili = 0.f, rmax = -1e30f;

    for (int tt = 0; tt < TSTEPS; ++tt) {
        if (wv == 0) {
            bool need = lane < SW;
            u64 w = 0;
            for (;;) {
                if (need) w = ald64(arch + (size_t)tt * SW + lane);
                bool ok = !need || (unsigned)(w >> 32) == (unsigned)(tt + 1);
                if (__ballot(ok) == ~0ull) break;
                __builtin_amdgcn_s_sleep(1);
            }
            if (need) zw[lane] = (unsigned)w;
        }
        __syncthreads();
        #pragma unroll
        for (int k = 0; k < R; ++k) {
            float p;
            if (ROLE) {
                unsigned bits = (zw[(t * 4) >> 5] >> ((t * 4) & 31)) & 0xFu;
                float4 w4 = ((const float4*)fcw)[k * (N / 4) + t];
                p = (bits & 1u ? w4.x : 0.f) + (bits & 2u ? w4.y : 0.f)
                  + (bits & 4u ? w4.z : 0.f) + (bits & 8u ? w4.w : 0.f);
            } else {
                unsigned bits = (zw[(t * 2) >> 5] >> ((t * 2) & 31)) & 0x3u;
                float2 w2 = ((const float2*)fcw)[k * (N / 2) + t];
                p = (bits & 1u ? w2.x : 0.f) + (bits & 2u ? w2.y : 0.f);
            }
            #pragma unroll
            for (int off = 32; off; off >>= 1) p += __shfl_xor(p, off);
            if (lane == 0) wpart[k * 4 + wv] = p;
        }
        __syncthreads();
        if (t < R) {
            float inp = wpart[t * 4] + wpart[t * 4 + 1] + wpart[t * 4 + 2] + wpart[t * 4 + 3];
            float vn = vli + 0.1f * (ili - vli);
            ili = ili - 0.2f * ili + inp;
            vli = vn;
            rmax = fmaxf(rmax, vn);
        }
    }
    if (ROLE) {
        if (t < 10) mvals[t] = rmax;
        __syncthreads();
        if (t < 10) {
            float M = -1e30f;
            #pragma unroll
            for (int k = 0; k < 10; ++k) M = fmaxf(M, mvals[k]);
            float ssum = 0.f;
            #pragma unroll
            for (int k = 0; k < 10; ++k) ssum += expf(mvals[k] - M);
            out[BATCH * 4 + b * 10 + t] = mvals[t] - M - logf(ssum);
        }
    } else if (t < 4) {
        out[b * 4 + t] = rmax;
    }
}

// -------------------------------------------------------------- fused ---
__global__ __launch_bounds__(256, 4) void snn_fused(
        const float* __restrict__ w2, const float* __restrict__ b2,
        const float* __restrict__ fc_out_w, const float* __restrict__ cl_fc_w,
        const float* __restrict__ w1t, const float* __restrict__ w2t,
        const float* __restrict__ c1buf,
        u64* __restrict__ arch1, u64* __restrict__ arch0,
        u64* __restrict__ archc,
        float* __restrict__ out, int b0, int BP) {
    __shared__ float smem[4096];      // 16.4 KB -> all WGs co-resident
    int bid = blockIdx.x;
    if (bid < 8 * BP) {                                 // conv
        int w = bid / BP, bl = bid - w * BP;
        int b = b0 + bl;
        conv_body(w, bl, w2, b2, c1buf,
                  archc + (size_t)b * TSTEPS * 8, smem);
    } else if (bid < 24 * BP) {                         // role-1 stripes
        int idx = bid - 8 * BP;
        int s = idx / BP, bl = idx - s * BP;
        int b = b0 + bl;
        stripe_body<1>(b, s, w2t, arch1 + (size_t)b * TSTEPS * 32,
                       archc + (size_t)b * TSTEPS * 8, smem);
    } else if (bid < 28 * BP) {                         // role-0 stripes
        int idx = bid - 24 * BP;
        int s = idx / BP, bl = idx - s * BP;
        int b = b0 + bl;
        stripe_body<0>(b, s, w1t, arch0 + (size_t)b * TSTEPS * 16,
                       archc + (size_t)b * TSTEPS * 8, smem);
    } else if (bid < 29 * BP) {
        int b = b0 + (bid - 28 * BP);
        readout_body<1>(b, cl_fc_w, arch1 + (size_t)b * TSTEPS * 32, out, smem);
    } else {
        int b = b0 + (bid - 29 * BP);
        readout_body<0>(b, fc_out_w, arch0 + (size_t)b * TSTEPS * 16, out, smem);
    }
}

// ---------------------------------------------------------------------------
extern "C" void kernel_launch(void* const* d_in, const int* in_sizes, int n_in,
                              void* d_out, int out_size, void* d_ws, size_t ws_size,
                              hipStream_t stream) {
    const float* x        = (const float*)d_in[0];
    const float* w1       = (const float*)d_in[1];
    const float* b1       = (const float*)d_in[2];
    const float* w2       = (const float*)d_in[3];
    const float* b2       = (const float*)d_in[4];
    const float* l1_in_w  = (const float*)d_in[5];
    const float* l1_rec_w = (const float*)d_in[6];
    const float* fc_out_w = (const float*)d_in[7];
    const float* cl_in_w  = (const float*)d_in[8];
    const float* cl_rec_w = (const float*)d_in[9];
    const float* cl_fc_w  = (const float*)d_in[10];
    float* out = (float*)d_out;

    u64* arch1  = (u64*)d_ws;
    u64* arch0  = arch1 + A1_U64;
    u64* archc  = arch0 + A0_U64;
    float* w1t  = (float*)(archc + AC_U64);
    float* w2t  = w1t + N_W1T;
    float* c1buf = w2t + N_W2T;

    // batch-pass size fitting ws (archives always full-size 32-batch)
    size_t head = 2 * (size_t)N_ARCH_U64 + N_W1T + N_W2T;   // floats
    size_t avail = ws_size / 4;
    int BP = 4;
    if (head + (size_t)32 * TSTEPS * C1N <= avail) BP = 32;
    else if (head + (size_t)16 * TSTEPS * C1N <= avail) BP = 16;
    else if (head + (size_t)8 * TSTEPS * C1N <= avail) BP = 8;

    prep_weights<<<dim3(512), dim3(256), 0, stream>>>(l1_in_w, l1_rec_w,
                                                      cl_in_w, cl_rec_w, w1t, w2t);
    init_arch<<<dim3(256), dim3(256), 0, stream>>>(arch1);
    for (int b0 = 0; b0 < BATCH; b0 += BP) {
        conv1_pool<<<dim3(BP * TSTEPS), dim3(640), 0, stream>>>(x, w1, b1, c1buf, b0);
        snn_fused<<<dim3(30 * BP), dim3(256), 0, stream>>>(w2, b2, fc_out_w, cl_fc_w,
                                                           w1t, w2t, c1buf,
                                                           arch1, arch0, archc,
                                                           out, b0, BP);
    }
}